// Round 1
// baseline (1096.101 us; speedup 1.0000x reference)
//
#include <hip/hip_runtime.h>
#include <math.h>

#define N_NODES 20000
#define F_IN    128
#define H_HEADS 5
#define HID     320
#define NHID    512
#define NOUT    256
#define G_GRAPHS 200

// ---------------- CSR build (dst -> list of src), self-loops included ----------------
__global__ void k_init_cnt(int* cnt) {
    int i = blockIdx.x * 256 + threadIdx.x;
    if (i < N_NODES) cnt[i] = 1;  // self loop
}

__global__ void k_hist(const int* __restrict__ ei, int* cnt, int E) {
    int e = blockIdx.x * 256 + threadIdx.x;
    if (e < E) atomicAdd(&cnt[ei[E + e]], 1);
}

__global__ __launch_bounds__(1024) void k_scan(const int* __restrict__ cnt, int* off, int* cur) {
    __shared__ int part[1024];
    int t = threadIdx.x;
    const int per = (N_NODES + 1023) / 1024;
    int base = t * per;
    int sum = 0;
    for (int i = 0; i < per; ++i) { int idx = base + i; if (idx < N_NODES) sum += cnt[idx]; }
    part[t] = sum;
    __syncthreads();
    for (int s = 1; s < 1024; s <<= 1) {
        int v = (t >= s) ? part[t - s] : 0;
        __syncthreads();
        part[t] += v;
        __syncthreads();
    }
    int run = (t == 0) ? 0 : part[t - 1];
    for (int i = 0; i < per; ++i) {
        int idx = base + i;
        if (idx < N_NODES) { off[idx] = run; cur[idx] = run; run += cnt[idx]; }
    }
    if (t == 1023) off[N_NODES] = part[1023];
}

__global__ void k_fill_self(int* cur, int* srcl) {
    int i = blockIdx.x * 256 + threadIdx.x;
    if (i < N_NODES) { int p = atomicAdd(&cur[i], 1); srcl[p] = i; }
}

__global__ void k_fill_edge(const int* __restrict__ ei, int* cur, int* srcl, int E) {
    int e = blockIdx.x * 256 + threadIdx.x;
    if (e < E) { int d = ei[E + e]; int p = atomicAdd(&cur[d], 1); srcl[p] = ei[e]; }
}

// ---------------- f32 GEMM: C[M,320] = A[M,K] @ B[K,320] (+ optional bias) ----------------
#define BM 128
#define BN 64
#define BK 16
__global__ __launch_bounds__(256) void k_gemm(const float* __restrict__ A, const float* __restrict__ B,
                                              const float* __restrict__ bias, float* __restrict__ C,
                                              int M, int K) {
    __shared__ float As[BK][BM + 4];   // stride 132: 2-way max on writes (free)
    __shared__ float Bs[BK][BN];
    int t = threadIdx.x;
    int tx = t & 15, ty = t >> 4;
    int m0 = blockIdx.y * BM, n0 = blockIdx.x * BN;
    float acc[8][4];
#pragma unroll
    for (int i = 0; i < 8; ++i)
#pragma unroll
        for (int j = 0; j < 4; ++j) acc[i][j] = 0.f;

    for (int k0 = 0; k0 < K; k0 += BK) {
#pragma unroll
        for (int i = 0; i < 8; ++i) {        // A tile 128x16
            int idx = t + i * 256;           // 0..2047
            int am = idx >> 4, ak = idx & 15;
            int gm = m0 + am;
            As[ak][am] = (gm < M) ? A[(size_t)gm * K + k0 + ak] : 0.f;
        }
#pragma unroll
        for (int i = 0; i < 4; ++i) {        // B tile 16x64
            int idx = t + i * 256;           // 0..1023
            int bk = idx >> 6, bn = idx & 63;
            Bs[bk][bn] = B[(size_t)(k0 + bk) * HID + n0 + bn];
        }
        __syncthreads();
#pragma unroll
        for (int kk = 0; kk < BK; ++kk) {
            float a[8], b[4];
#pragma unroll
            for (int i = 0; i < 8; ++i) a[i] = As[kk][ty * 8 + i];
#pragma unroll
            for (int j = 0; j < 4; ++j) b[j] = Bs[kk][tx * 4 + j];
#pragma unroll
            for (int i = 0; i < 8; ++i)
#pragma unroll
                for (int j = 0; j < 4; ++j) acc[i][j] += a[i] * b[j];
        }
        __syncthreads();
    }
#pragma unroll
    for (int i = 0; i < 8; ++i) {
        int gm = m0 + ty * 8 + i;
        if (gm < M) {
#pragma unroll
            for (int j = 0; j < 4; ++j) {
                int gn = n0 + tx * 4 + j;
                float v = acc[i][j];
                if (bias) v += bias[gn];
                C[(size_t)gm * HID + gn] = v;
            }
        }
    }
}

// ---------------- per-node attention coefficients s,d ----------------
__global__ __launch_bounds__(256) void k_sd(const float* __restrict__ hg, const float* __restrict__ a_s,
                                            const float* __restrict__ a_d,
                                            float* __restrict__ s, float* __restrict__ d) {
    int wid = threadIdx.x >> 6;
    int lane = threadIdx.x & 63;
    int n = blockIdx.x * 4 + wid;
    if (n >= N_NODES) return;
#pragma unroll
    for (int h = 0; h < H_HEADS; ++h) {
        float v = hg[(size_t)n * HID + h * 64 + lane];
        float ps = v * a_s[h * 64 + lane];
        float pd = v * a_d[h * 64 + lane];
#pragma unroll
        for (int w = 32; w >= 1; w >>= 1) {
            ps += __shfl_xor(ps, w, 64);
            pd += __shfl_xor(pd, w, 64);
        }
        if (lane == 0) { s[n * H_HEADS + h] = ps; d[n * H_HEADS + h] = pd; }
    }
}

// ---------------- GAT aggregation: softmax over in-edges + weighted sum, fused epilogue ----------------
// out[i] = base[i] + relu(agg_i/den + bias)   (one wave per dst node; 4 waves per block)
__global__ __launch_bounds__(256) void k_agg(const float* __restrict__ hg, const float* __restrict__ s,
                                             const float* __restrict__ dd,
                                             const int* __restrict__ off, const int* __restrict__ srcl,
                                             const float* __restrict__ bias, const float* __restrict__ base,
                                             float* __restrict__ outp) {
    int wid = threadIdx.x >> 6;
    int lane = threadIdx.x & 63;
    int i = blockIdx.x * 4 + wid;
    if (i >= N_NODES) return;
    int o0 = off[i], o1 = off[i + 1];
    int deg = o1 - o0;

    float di[H_HEADS];
#pragma unroll
    for (int h = 0; h < H_HEADS; ++h) di[h] = dd[i * H_HEADS + h];

    // phase A: per-head max over edges
    float m[H_HEADS];
#pragma unroll
    for (int h = 0; h < H_HEADS; ++h) m[h] = -1e30f;
    for (int j = lane; j < deg; j += 64) {
        int sj = srcl[o0 + j];
#pragma unroll
        for (int h = 0; h < H_HEADS; ++h) {
            float e = s[sj * H_HEADS + h] + di[h];
            e = (e >= 0.f) ? e : 0.2f * e;
            m[h] = fmaxf(m[h], e);
        }
    }
#pragma unroll
    for (int w = 32; w >= 1; w >>= 1)
#pragma unroll
        for (int h = 0; h < H_HEADS; ++h) m[h] = fmaxf(m[h], __shfl_xor(m[h], w, 64));

    // phase B: exp, denominator, weighted gather (shuffle-broadcast per edge, no LDS)
    float acc[H_HEADS] = {0.f, 0.f, 0.f, 0.f, 0.f};
    float den[H_HEADS] = {0.f, 0.f, 0.f, 0.f, 0.f};
    for (int cb = 0; cb < deg; cb += 64) {
        int j = cb + lane;
        int sj = 0;
        float exl[H_HEADS] = {0.f, 0.f, 0.f, 0.f, 0.f};
        if (j < deg) {
            sj = srcl[o0 + j];
#pragma unroll
            for (int h = 0; h < H_HEADS; ++h) {
                float e = s[sj * H_HEADS + h] + di[h];
                e = (e >= 0.f) ? e : 0.2f * e;
                float ex = expf(e - m[h]);
                exl[h] = ex;
                den[h] += ex;
            }
        }
        int cnt = min(64, deg - cb);
        for (int jj = 0; jj < cnt; ++jj) {
            int sjj = __shfl(sj, jj, 64);
            const float* row = hg + (size_t)sjj * HID;
            float w0 = __shfl(exl[0], jj, 64);
            float w1 = __shfl(exl[1], jj, 64);
            float w2 = __shfl(exl[2], jj, 64);
            float w3 = __shfl(exl[3], jj, 64);
            float w4 = __shfl(exl[4], jj, 64);
            acc[0] += w0 * row[0 * 64 + lane];
            acc[1] += w1 * row[1 * 64 + lane];
            acc[2] += w2 * row[2 * 64 + lane];
            acc[3] += w3 * row[3 * 64 + lane];
            acc[4] += w4 * row[4 * 64 + lane];
        }
    }
#pragma unroll
    for (int w = 32; w >= 1; w >>= 1)
#pragma unroll
        for (int h = 0; h < H_HEADS; ++h) den[h] += __shfl_xor(den[h], w, 64);

#pragma unroll
    for (int h = 0; h < H_HEADS; ++h) {
        int col = h * 64 + lane;
        float v = acc[h] / den[h] + bias[col];
        v = fmaxf(v, 0.f);
        outp[(size_t)i * HID + col] = base[(size_t)i * HID + col] + v;
    }
}

// ---------------- pooling: segment mean over sorted batch ----------------
__global__ __launch_bounds__(320) void k_pool(const float* __restrict__ h, const int* __restrict__ batch,
                                              float* __restrict__ pooled) {
    int g = blockIdx.x;
    int t = threadIdx.x;  // 320
    int lo = 0, hi = N_NODES;
    while (lo < hi) { int mid = (lo + hi) >> 1; if (batch[mid] < g) lo = mid + 1; else hi = mid; }
    int start = lo;
    hi = N_NODES;
    while (lo < hi) { int mid = (lo + hi) >> 1; if (batch[mid] < g + 1) lo = mid + 1; else hi = mid; }
    int end = lo;
    float acc = 0.f;
    for (int r = start; r < end; ++r) acc += h[(size_t)r * HID + t];
    float cntf = (float)(end - start);
    pooled[g * HID + t] = acc / fmaxf(cntf, 1.f);
}

// ---------------- MLP head ----------------
__global__ __launch_bounds__(64) void k_mlp1(const float* __restrict__ pooled, const float* __restrict__ W,
                                             const float* __restrict__ b, float* __restrict__ z1) {
    int r = blockIdx.x;
    int col = blockIdx.y * 64 + threadIdx.x;
    float acc = 0.f;
    for (int k = 0; k < HID; ++k) acc += pooled[r * HID + k] * W[k * NHID + col];
    acc += b[col];
    z1[r * NHID + col] = fmaxf(acc, 0.f);
}

__global__ __launch_bounds__(256) void k_mlp2_ln(const float* __restrict__ z1, const float* __restrict__ W,
                                                 const float* __restrict__ b, const float* __restrict__ g_,
                                                 const float* __restrict__ beta, float* __restrict__ outp) {
    int r = blockIdx.x;
    int col = threadIdx.x;  // 256
    float acc = 0.f;
    for (int k = 0; k < NHID; ++k) acc += z1[r * NHID + k] * W[k * NOUT + col];
    acc += b[col];
    __shared__ float red[256];
    red[col] = acc;
    __syncthreads();
    for (int s = 128; s > 0; s >>= 1) { if (col < s) red[col] += red[col + s]; __syncthreads(); }
    float mu = red[0] / (float)NOUT;
    __syncthreads();
    float dv = acc - mu;
    red[col] = dv * dv;
    __syncthreads();
    for (int s = 128; s > 0; s >>= 1) { if (col < s) red[col] += red[col + s]; __syncthreads(); }
    float var = red[0] / (float)NOUT;
    outp[r * NOUT + col] = g_[col] * dv * rsqrtf(var + 1e-5f) + beta[col];
}

// ---------------- launch ----------------
extern "C" void kernel_launch(void* const* d_in, const int* in_sizes, int n_in,
                              void* d_out, int out_size, void* d_ws, size_t ws_size,
                              hipStream_t stream) {
    const float* x     = (const float*)d_in[0];
    const int*   ei    = (const int*)d_in[1];
    const int*   batch = (const int*)d_in[2];
    const float *W[5], *as_[5], *ad_[5], *bb[5];
    int idx = 3;
    for (int l = 0; l < 5; ++l) {
        W[l]   = (const float*)d_in[idx++];
        as_[l] = (const float*)d_in[idx++];
        ad_[l] = (const float*)d_in[idx++];
        bb[l]  = (const float*)d_in[idx++];
    }
    const float* Wm1 = (const float*)d_in[idx++];
    const float* bm1 = (const float*)d_in[idx++];
    const float* Wm2 = (const float*)d_in[idx++];
    const float* bm2 = (const float*)d_in[idx++];
    const float* Wh1 = (const float*)d_in[idx++];
    const float* bh1 = (const float*)d_in[idx++];
    const float* Wh2 = (const float*)d_in[idx++];
    const float* bh2 = (const float*)d_in[idx++];
    const float* lng = (const float*)d_in[idx++];
    const float* lnb = (const float*)d_in[idx++];

    const int E = in_sizes[1] / 2;
    float* out = (float*)d_out;

    char* ws = (char*)d_ws;
    size_t o = 0;
    auto alloc = [&](size_t bytes) -> char* {
        char* p = ws + o;
        o += bytes;
        o = (o + 255) & ~(size_t)255;
        return p;
    };
    const size_t NB = (size_t)N_NODES * HID * sizeof(float);
    float* big0   = (float*)alloc(NB);
    float* big1   = (float*)alloc(NB);
    float* big2   = (float*)alloc(NB);
    float* sbuf   = (float*)alloc((size_t)N_NODES * H_HEADS * sizeof(float));
    float* dbuf   = (float*)alloc((size_t)N_NODES * H_HEADS * sizeof(float));
    int*   cnt    = (int*)alloc((size_t)N_NODES * sizeof(int));
    int*   off    = (int*)alloc((size_t)(N_NODES + 1) * sizeof(int));
    int*   cur    = (int*)alloc((size_t)N_NODES * sizeof(int));
    int*   srcl   = (int*)alloc((size_t)(E + N_NODES) * sizeof(int));
    float* pooled = (float*)alloc((size_t)G_GRAPHS * HID * sizeof(float));
    float* z1     = (float*)alloc((size_t)G_GRAPHS * NHID * sizeof(float));

    // CSR
    k_init_cnt<<<(N_NODES + 255) / 256, 256, 0, stream>>>(cnt);
    k_hist<<<(E + 255) / 256, 256, 0, stream>>>(ei, cnt, E);
    k_scan<<<1, 1024, 0, stream>>>(cnt, off, cur);
    k_fill_self<<<(N_NODES + 255) / 256, 256, 0, stream>>>(cur, srcl);
    k_fill_edge<<<(E + 255) / 256, 256, 0, stream>>>(ei, cur, srcl, E);

    dim3 gemm_grid(HID / BN, (N_NODES + BM - 1) / BM);
    dim3 agg_grid((N_NODES + 3) / 4);

    // Layer 1: x0 = relu(gat(x; W1)); h = (x@Wm1+bm1) + x0  -> big1
    k_gemm<<<gemm_grid, 256, 0, stream>>>(x, W[0], nullptr, big0, N_NODES, F_IN);
    k_gemm<<<gemm_grid, 256, 0, stream>>>(x, Wm1, bm1, big1, N_NODES, F_IN);
    k_sd<<<(N_NODES + 3) / 4, 256, 0, stream>>>(big0, as_[0], ad_[0], sbuf, dbuf);
    k_agg<<<agg_grid, 256, 0, stream>>>(big0, sbuf, dbuf, off, srcl, bb[0], big1, big1);

    // Layer 2: x1 = relu(gat(h; W2)); h = (h@Wm2+bm2) + x1 -> big2
    k_gemm<<<gemm_grid, 256, 0, stream>>>(big1, W[1], nullptr, big0, N_NODES, HID);
    k_gemm<<<gemm_grid, 256, 0, stream>>>(big1, Wm2, bm2, big2, N_NODES, HID);
    k_sd<<<(N_NODES + 3) / 4, 256, 0, stream>>>(big0, as_[1], ad_[1], sbuf, dbuf);
    k_agg<<<agg_grid, 256, 0, stream>>>(big0, sbuf, dbuf, off, srcl, bb[1], big2, big2);

    // Layers 3-5: h = h + relu(gat(h; Wl))  (in place on big2)
    for (int l = 2; l < 5; ++l) {
        k_gemm<<<gemm_grid, 256, 0, stream>>>(big2, W[l], nullptr, big0, N_NODES, HID);
        k_sd<<<(N_NODES + 3) / 4, 256, 0, stream>>>(big0, as_[l], ad_[l], sbuf, dbuf);
        k_agg<<<agg_grid, 256, 0, stream>>>(big0, sbuf, dbuf, off, srcl, bb[l], big2, big2);
    }

    // pool + head
    k_pool<<<G_GRAPHS, HID, 0, stream>>>(big2, batch, pooled);
    k_mlp1<<<dim3(G_GRAPHS, NHID / 64), 64, 0, stream>>>(pooled, Wh1, bh1, z1);
    k_mlp2_ln<<<G_GRAPHS, NOUT, 0, stream>>>(z1, Wh2, bh2, lng, lnb, out);
}

// Round 2
// 701.027 us; speedup vs baseline: 1.5636x; 1.5636x over previous
//
#include <hip/hip_runtime.h>
#include <math.h>

#define N_NODES 20000
#define F_IN    128
#define H_HEADS 5
#define HID     320
#define NHID    512
#define NOUT    256
#define G_GRAPHS 200

typedef __attribute__((ext_vector_type(8))) short bf16x8;
typedef __attribute__((ext_vector_type(4))) float f32x4;

__device__ __forceinline__ unsigned short f2bf(float f) {
    unsigned int u = __float_as_uint(f);
    u += 0x7fffu + ((u >> 16) & 1u);
    return (unsigned short)(u >> 16);
}

// ---------------- CSR build (dst -> list of src), self-loops included ----------------
__global__ void k_init_cnt(int* cnt) {
    int i = blockIdx.x * 256 + threadIdx.x;
    if (i < N_NODES) cnt[i] = 1;  // self loop
}

__global__ void k_hist(const int* __restrict__ ei, int* cnt, int E) {
    int e = blockIdx.x * 256 + threadIdx.x;
    if (e < E) atomicAdd(&cnt[ei[E + e]], 1);
}

__global__ __launch_bounds__(1024) void k_scan(const int* __restrict__ cnt, int* off, int* cur) {
    __shared__ int part[1024];
    int t = threadIdx.x;
    const int per = (N_NODES + 1023) / 1024;
    int base = t * per;
    int sum = 0;
    for (int i = 0; i < per; ++i) { int idx = base + i; if (idx < N_NODES) sum += cnt[idx]; }
    part[t] = sum;
    __syncthreads();
    for (int s = 1; s < 1024; s <<= 1) {
        int v = (t >= s) ? part[t - s] : 0;
        __syncthreads();
        part[t] += v;
        __syncthreads();
    }
    int run = (t == 0) ? 0 : part[t - 1];
    for (int i = 0; i < per; ++i) {
        int idx = base + i;
        if (idx < N_NODES) { off[idx] = run; cur[idx] = run; run += cnt[idx]; }
    }
    if (t == 1023) off[N_NODES] = part[1023];
}

__global__ void k_fill_self(int* cur, int* srcl) {
    int i = blockIdx.x * 256 + threadIdx.x;
    if (i < N_NODES) { int p = atomicAdd(&cur[i], 1); srcl[p] = i; }
}

__global__ void k_fill_edge(const int* __restrict__ ei, int* cur, int* srcl, int E) {
    int e = blockIdx.x * 256 + threadIdx.x;
    if (e < E) { int d = ei[E + e]; int p = atomicAdd(&cur[d], 1); srcl[p] = ei[e]; }
}

// ---------------- conversions ----------------
__global__ void k_cvt(const float* __restrict__ in, unsigned short* __restrict__ outp, int n) {
    int i = blockIdx.x * 256 + threadIdx.x;
    if (i < n) outp[i] = f2bf(in[i]);
}

// W [K,320] f32 row-major -> Wt [320,K] bf16 (n-major, k contiguous)
__global__ void k_wt(const float* __restrict__ W, unsigned short* __restrict__ Wt, int K, int n) {
    int i = blockIdx.x * 256 + threadIdx.x;
    if (i < n) {
        int nn = i / K, k = i - nn * K;
        Wt[i] = f2bf(W[(size_t)k * HID + nn]);
    }
}

// ---------------- bf16 MFMA GEMM: C[M,320] = A[M,K] @ B[K,320] (+bias) ----------------
// A bf16 [M,K]; Bt bf16 [320,K] (transposed). blockIdx.z==1 selects the second (Bt2,bias2,C2) problem.
#define GM 128
#define GN 64
#define GK 64
#define GKP 72   // padded LDS stride: 144 B/row = +4 banks/row -> <=2-way conflicts (free)

__global__ __launch_bounds__(256) void k_gemm_mfma(
    const unsigned short* __restrict__ A,
    const unsigned short* __restrict__ Bt,
    const float* __restrict__ bias,
    float* __restrict__ C,
    const unsigned short* __restrict__ Bt2,
    const float* __restrict__ bias2,
    float* __restrict__ C2,
    int M, int K)
{
    if (blockIdx.z == 1) { Bt = Bt2; bias = bias2; C = C2; }
    __shared__ unsigned short As[GM][GKP];
    __shared__ unsigned short Bs[GN][GKP];
    int tid = threadIdx.x;
    int lane = tid & 63, wid = tid >> 6;
    int wr = wid >> 1, wc = wid & 1;          // 2x2 wave grid
    int q = lane >> 4, r16 = lane & 15;
    int m0 = blockIdx.y * GM, n0 = blockIdx.x * GN;

    f32x4 acc[4][2];
#pragma unroll
    for (int mi = 0; mi < 4; ++mi)
#pragma unroll
        for (int ni = 0; ni < 2; ++ni)
#pragma unroll
            for (int r = 0; r < 4; ++r) acc[mi][ni][r] = 0.f;

    for (int k0 = 0; k0 < K; k0 += GK) {
        // stage A tile 128x64 (bf16, 16B per thread-iter)
#pragma unroll
        for (int i = 0; i < 4; ++i) {
            int idx = tid + i * 256;          // 0..1023
            int m = idx >> 3, g = idx & 7;
            int row = m0 + m;
            bf16x8 v;
            if (row < M) v = *(const bf16x8*)(A + (size_t)row * K + k0 + g * 8);
            else { for (int j = 0; j < 8; ++j) v[j] = 0; }
            *(bf16x8*)&As[m][g * 8] = v;
        }
        // stage B tile (transposed): Bs[n][k] from Bt[n0+n][k0..]
#pragma unroll
        for (int i = 0; i < 2; ++i) {
            int idx = tid + i * 256;          // 0..511
            int nn = idx >> 3, g = idx & 7;
            bf16x8 v = *(const bf16x8*)(Bt + (size_t)(n0 + nn) * K + k0 + g * 8);
            *(bf16x8*)&Bs[nn][g * 8] = v;
        }
        __syncthreads();
#pragma unroll
        for (int kc = 0; kc < 2; ++kc) {
            bf16x8 av[4], bv[2];
#pragma unroll
            for (int mi = 0; mi < 4; ++mi)
                av[mi] = *(const bf16x8*)&As[wr * 64 + mi * 16 + r16][kc * 32 + q * 8];
#pragma unroll
            for (int ni = 0; ni < 2; ++ni)
                bv[ni] = *(const bf16x8*)&Bs[wc * 32 + ni * 16 + r16][kc * 32 + q * 8];
#pragma unroll
            for (int mi = 0; mi < 4; ++mi)
#pragma unroll
                for (int ni = 0; ni < 2; ++ni)
                    acc[mi][ni] = __builtin_amdgcn_mfma_f32_16x16x32_bf16(av[mi], bv[ni], acc[mi][ni], 0, 0, 0);
        }
        __syncthreads();
    }

#pragma unroll
    for (int mi = 0; mi < 4; ++mi)
#pragma unroll
        for (int ni = 0; ni < 2; ++ni) {
            int col = n0 + wc * 32 + ni * 16 + r16;
            float bval = bias ? bias[col] : 0.f;
#pragma unroll
            for (int r = 0; r < 4; ++r) {
                int row = m0 + wr * 64 + mi * 16 + q * 4 + r;
                if (row < M) C[(size_t)row * HID + col] = acc[mi][ni][r] + bval;
            }
        }
}

// ---------------- per-node attention coefficients s,d ----------------
__global__ __launch_bounds__(256) void k_sd(const float* __restrict__ hg, const float* __restrict__ a_s,
                                            const float* __restrict__ a_d,
                                            float* __restrict__ s, float* __restrict__ d) {
    int wid = threadIdx.x >> 6;
    int lane = threadIdx.x & 63;
    int n = blockIdx.x * 4 + wid;
    if (n >= N_NODES) return;
#pragma unroll
    for (int h = 0; h < H_HEADS; ++h) {
        float v = hg[(size_t)n * HID + h * 64 + lane];
        float ps = v * a_s[h * 64 + lane];
        float pd = v * a_d[h * 64 + lane];
#pragma unroll
        for (int w = 32; w >= 1; w >>= 1) {
            ps += __shfl_xor(ps, w, 64);
            pd += __shfl_xor(pd, w, 64);
        }
        if (lane == 0) { s[n * H_HEADS + h] = ps; d[n * H_HEADS + h] = pd; }
    }
}

// ---------------- GAT aggregation: softmax over in-edges + weighted sum, fused epilogue ----------------
// out[i] = base[i] + relu(agg_i/den + bias); also writes bf16 mirror for the next layer's GEMM A.
__global__ __launch_bounds__(256) void k_agg(const float* __restrict__ hg, const float* __restrict__ s,
                                             const float* __restrict__ dd,
                                             const int* __restrict__ off, const int* __restrict__ srcl,
                                             const float* __restrict__ bias, const float* __restrict__ base,
                                             float* __restrict__ outp, unsigned short* __restrict__ out_bf) {
    int wid = threadIdx.x >> 6;
    int lane = threadIdx.x & 63;
    int i = blockIdx.x * 4 + wid;
    if (i >= N_NODES) return;
    int o0 = off[i], o1 = off[i + 1];
    int deg = o1 - o0;

    float di[H_HEADS];
#pragma unroll
    for (int h = 0; h < H_HEADS; ++h) di[h] = dd[i * H_HEADS + h];

    // phase A: per-head max over edges
    float m[H_HEADS];
#pragma unroll
    for (int h = 0; h < H_HEADS; ++h) m[h] = -1e30f;
    for (int j = lane; j < deg; j += 64) {
        int sj = srcl[o0 + j];
#pragma unroll
        for (int h = 0; h < H_HEADS; ++h) {
            float e = s[sj * H_HEADS + h] + di[h];
            e = (e >= 0.f) ? e : 0.2f * e;
            m[h] = fmaxf(m[h], e);
        }
    }
#pragma unroll
    for (int w = 32; w >= 1; w >>= 1)
#pragma unroll
        for (int h = 0; h < H_HEADS; ++h) m[h] = fmaxf(m[h], __shfl_xor(m[h], w, 64));

    // phase B: exp, denominator, weighted gather
    float acc[H_HEADS] = {0.f, 0.f, 0.f, 0.f, 0.f};
    float den[H_HEADS] = {0.f, 0.f, 0.f, 0.f, 0.f};
    for (int cb = 0; cb < deg; cb += 64) {
        int j = cb + lane;
        int sj = 0;
        float exl[H_HEADS] = {0.f, 0.f, 0.f, 0.f, 0.f};
        if (j < deg) {
            sj = srcl[o0 + j];
#pragma unroll
            for (int h = 0; h < H_HEADS; ++h) {
                float e = s[sj * H_HEADS + h] + di[h];
                e = (e >= 0.f) ? e : 0.2f * e;
                float ex = expf(e - m[h]);
                exl[h] = ex;
                den[h] += ex;
            }
        }
        int cnt = min(64, deg - cb);
        for (int jj = 0; jj < cnt; ++jj) {
            int sjj = __shfl(sj, jj, 64);
            const float* row = hg + (size_t)sjj * HID;
            float w0 = __shfl(exl[0], jj, 64);
            float w1 = __shfl(exl[1], jj, 64);
            float w2 = __shfl(exl[2], jj, 64);
            float w3 = __shfl(exl[3], jj, 64);
            float w4 = __shfl(exl[4], jj, 64);
            acc[0] += w0 * row[0 * 64 + lane];
            acc[1] += w1 * row[1 * 64 + lane];
            acc[2] += w2 * row[2 * 64 + lane];
            acc[3] += w3 * row[3 * 64 + lane];
            acc[4] += w4 * row[4 * 64 + lane];
        }
    }
#pragma unroll
    for (int w = 32; w >= 1; w >>= 1)
#pragma unroll
        for (int h = 0; h < H_HEADS; ++h) den[h] += __shfl_xor(den[h], w, 64);

#pragma unroll
    for (int h = 0; h < H_HEADS; ++h) {
        int col = h * 64 + lane;
        float v = acc[h] / den[h] + bias[col];
        v = fmaxf(v, 0.f);
        float outv = base[(size_t)i * HID + col] + v;
        outp[(size_t)i * HID + col] = outv;
        out_bf[(size_t)i * HID + col] = f2bf(outv);
    }
}

// ---------------- pooling: segment mean over sorted batch ----------------
__global__ __launch_bounds__(320) void k_pool(const float* __restrict__ h, const int* __restrict__ batch,
                                              float* __restrict__ pooled) {
    int g = blockIdx.x;
    int t = threadIdx.x;  // 320
    int lo = 0, hi = N_NODES;
    while (lo < hi) { int mid = (lo + hi) >> 1; if (batch[mid] < g) lo = mid + 1; else hi = mid; }
    int start = lo;
    hi = N_NODES;
    while (lo < hi) { int mid = (lo + hi) >> 1; if (batch[mid] < g + 1) lo = mid + 1; else hi = mid; }
    int end = lo;
    float acc = 0.f;
    for (int r = start; r < end; ++r) acc += h[(size_t)r * HID + t];
    float cntf = (float)(end - start);
    pooled[g * HID + t] = acc / fmaxf(cntf, 1.f);
}

// ---------------- MLP head ----------------
__global__ __launch_bounds__(64) void k_mlp1(const float* __restrict__ pooled, const float* __restrict__ W,
                                             const float* __restrict__ b, float* __restrict__ z1) {
    int r = blockIdx.x;
    int col = blockIdx.y * 64 + threadIdx.x;
    float acc = 0.f;
    for (int k = 0; k < HID; ++k) acc += pooled[r * HID + k] * W[k * NHID + col];
    acc += b[col];
    z1[r * NHID + col] = fmaxf(acc, 0.f);
}

__global__ __launch_bounds__(256) void k_mlp2_ln(const float* __restrict__ z1, const float* __restrict__ W,
                                                 const float* __restrict__ b, const float* __restrict__ g_,
                                                 const float* __restrict__ beta, float* __restrict__ outp) {
    int r = blockIdx.x;
    int col = threadIdx.x;  // 256
    float acc = 0.f;
    for (int k = 0; k < NHID; ++k) acc += z1[r * NHID + k] * W[k * NOUT + col];
    acc += b[col];
    __shared__ float red[256];
    red[col] = acc;
    __syncthreads();
    for (int s = 128; s > 0; s >>= 1) { if (col < s) red[col] += red[col + s]; __syncthreads(); }
    float mu = red[0] / (float)NOUT;
    __syncthreads();
    float dv = acc - mu;
    red[col] = dv * dv;
    __syncthreads();
    for (int s = 128; s > 0; s >>= 1) { if (col < s) red[col] += red[col + s]; __syncthreads(); }
    float var = red[0] / (float)NOUT;
    outp[r * NOUT + col] = g_[col] * dv * rsqrtf(var + 1e-5f) + beta[col];
}

// ---------------- launch ----------------
extern "C" void kernel_launch(void* const* d_in, const int* in_sizes, int n_in,
                              void* d_out, int out_size, void* d_ws, size_t ws_size,
                              hipStream_t stream) {
    const float* x     = (const float*)d_in[0];
    const int*   ei    = (const int*)d_in[1];
    const int*   batch = (const int*)d_in[2];
    const float *W[5], *as_[5], *ad_[5], *bb[5];
    int idx = 3;
    for (int l = 0; l < 5; ++l) {
        W[l]   = (const float*)d_in[idx++];
        as_[l] = (const float*)d_in[idx++];
        ad_[l] = (const float*)d_in[idx++];
        bb[l]  = (const float*)d_in[idx++];
    }
    const float* Wm1 = (const float*)d_in[idx++];
    const float* bm1 = (const float*)d_in[idx++];
    const float* Wm2 = (const float*)d_in[idx++];
    const float* bm2 = (const float*)d_in[idx++];
    const float* Wh1 = (const float*)d_in[idx++];
    const float* bh1 = (const float*)d_in[idx++];
    const float* Wh2 = (const float*)d_in[idx++];
    const float* bh2 = (const float*)d_in[idx++];
    const float* lng = (const float*)d_in[idx++];
    const float* lnb = (const float*)d_in[idx++];

    const int E = in_sizes[1] / 2;
    float* out = (float*)d_out;

    char* ws = (char*)d_ws;
    size_t o = 0;
    auto alloc = [&](size_t bytes) -> char* {
        char* p = ws + o;
        o += bytes;
        o = (o + 255) & ~(size_t)255;
        return p;
    };
    const size_t NB = (size_t)N_NODES * HID * sizeof(float);
    float* big0   = (float*)alloc(NB);
    float* big1   = (float*)alloc(NB);
    float* big2   = (float*)alloc(NB);
    float* sbuf   = (float*)alloc((size_t)N_NODES * H_HEADS * sizeof(float));
    float* dbuf   = (float*)alloc((size_t)N_NODES * H_HEADS * sizeof(float));
    int*   cnt    = (int*)alloc((size_t)N_NODES * sizeof(int));
    int*   off    = (int*)alloc((size_t)(N_NODES + 1) * sizeof(int));
    int*   cur    = (int*)alloc((size_t)N_NODES * sizeof(int));
    int*   srcl   = (int*)alloc((size_t)(E + N_NODES) * sizeof(int));
    float* pooled = (float*)alloc((size_t)G_GRAPHS * HID * sizeof(float));
    float* z1     = (float*)alloc((size_t)G_GRAPHS * NHID * sizeof(float));
    unsigned short* x_bf = (unsigned short*)alloc((size_t)N_NODES * F_IN * sizeof(short));
    unsigned short* h_bf = (unsigned short*)alloc((size_t)N_NODES * HID * sizeof(short));
    unsigned short* Wt1  = (unsigned short*)alloc((size_t)HID * F_IN * sizeof(short));
    unsigned short* Wtm1 = (unsigned short*)alloc((size_t)HID * F_IN * sizeof(short));
    unsigned short* Wt2  = (unsigned short*)alloc((size_t)HID * HID * sizeof(short));
    unsigned short* Wtm2 = (unsigned short*)alloc((size_t)HID * HID * sizeof(short));
    unsigned short* Wt3  = (unsigned short*)alloc((size_t)HID * HID * sizeof(short));
    unsigned short* Wt4  = (unsigned short*)alloc((size_t)HID * HID * sizeof(short));
    unsigned short* Wt5  = (unsigned short*)alloc((size_t)HID * HID * sizeof(short));

    // CSR
    k_init_cnt<<<(N_NODES + 255) / 256, 256, 0, stream>>>(cnt);
    k_hist<<<(E + 255) / 256, 256, 0, stream>>>(ei, cnt, E);
    k_scan<<<1, 1024, 0, stream>>>(cnt, off, cur);
    k_fill_self<<<(N_NODES + 255) / 256, 256, 0, stream>>>(cur, srcl);
    k_fill_edge<<<(E + 255) / 256, 256, 0, stream>>>(ei, cur, srcl, E);

    // conversions
    {
        int n = N_NODES * F_IN;
        k_cvt<<<(n + 255) / 256, 256, 0, stream>>>(x, x_bf, n);
        int nw_small = HID * F_IN;
        int nw_big = HID * HID;
        k_wt<<<(nw_small + 255) / 256, 256, 0, stream>>>(W[0], Wt1, F_IN, nw_small);
        k_wt<<<(nw_small + 255) / 256, 256, 0, stream>>>(Wm1, Wtm1, F_IN, nw_small);
        k_wt<<<(nw_big + 255) / 256, 256, 0, stream>>>(W[1], Wt2, HID, nw_big);
        k_wt<<<(nw_big + 255) / 256, 256, 0, stream>>>(Wm2, Wtm2, HID, nw_big);
        k_wt<<<(nw_big + 255) / 256, 256, 0, stream>>>(W[2], Wt3, HID, nw_big);
        k_wt<<<(nw_big + 255) / 256, 256, 0, stream>>>(W[3], Wt4, HID, nw_big);
        k_wt<<<(nw_big + 255) / 256, 256, 0, stream>>>(W[4], Wt5, HID, nw_big);
    }

    dim3 gemm_grid2(HID / GN, (N_NODES + GM - 1) / GM, 2);
    dim3 gemm_grid1(HID / GN, (N_NODES + GM - 1) / GM, 1);
    dim3 agg_grid((N_NODES + 3) / 4);

    // Layer 1: big0 = x@W1; big1 = x@Wm1+bm1 (batched); then agg -> big1, h_bf
    k_gemm_mfma<<<gemm_grid2, 256, 0, stream>>>(x_bf, Wt1, nullptr, big0, Wtm1, bm1, big1, N_NODES, F_IN);
    k_sd<<<(N_NODES + 3) / 4, 256, 0, stream>>>(big0, as_[0], ad_[0], sbuf, dbuf);
    k_agg<<<agg_grid, 256, 0, stream>>>(big0, sbuf, dbuf, off, srcl, bb[0], big1, big1, h_bf);

    // Layer 2: big0 = h@W2; big2 = h@Wm2+bm2 (batched); then agg -> big2, h_bf
    k_gemm_mfma<<<gemm_grid2, 256, 0, stream>>>(h_bf, Wt2, nullptr, big0, Wtm2, bm2, big2, N_NODES, HID);
    k_sd<<<(N_NODES + 3) / 4, 256, 0, stream>>>(big0, as_[1], ad_[1], sbuf, dbuf);
    k_agg<<<agg_grid, 256, 0, stream>>>(big0, sbuf, dbuf, off, srcl, bb[1], big2, big2, h_bf);

    // Layers 3-5: h = h + relu(gat(h)) in place on big2
    const unsigned short* Wtl[3] = {Wt3, Wt4, Wt5};
    for (int l = 2; l < 5; ++l) {
        k_gemm_mfma<<<gemm_grid1, 256, 0, stream>>>(h_bf, Wtl[l - 2], nullptr, big0,
                                                    Wtl[l - 2], nullptr, big0, N_NODES, HID);
        k_sd<<<(N_NODES + 3) / 4, 256, 0, stream>>>(big0, as_[l], ad_[l], sbuf, dbuf);
        k_agg<<<agg_grid, 256, 0, stream>>>(big0, sbuf, dbuf, off, srcl, bb[l], big2, big2, h_bf);
    }

    // pool + head
    k_pool<<<G_GRAPHS, HID, 0, stream>>>(big2, batch, pooled);
    k_mlp1<<<dim3(G_GRAPHS, NHID / 64), 64, 0, stream>>>(pooled, Wh1, bh1, z1);
    k_mlp2_ln<<<G_GRAPHS, NOUT, 0, stream>>>(z1, Wh2, bh2, lng, lnb, out);
}

// Round 3
// 526.683 us; speedup vs baseline: 2.0811x; 1.3310x over previous
//
#include <hip/hip_runtime.h>
#include <math.h>

#define N_NODES 20000
#define F_IN    128
#define H_HEADS 5
#define HID     320
#define NHID    512
#define NOUT    256
#define G_GRAPHS 200

typedef __attribute__((ext_vector_type(8))) short bf16x8;
typedef __attribute__((ext_vector_type(4))) float f32x4;

__device__ __forceinline__ unsigned short f2bf(float f) {
    unsigned int u = __float_as_uint(f);
    u += 0x7fffu + ((u >> 16) & 1u);
    return (unsigned short)(u >> 16);
}
__device__ __forceinline__ float bf2f(unsigned short u) {
    return __uint_as_float(((unsigned int)u) << 16);
}

// ---------------- CSR build (dst -> list of src), self-loops included ----------------
__global__ void k_init_cnt(int* cnt) {
    int i = blockIdx.x * 256 + threadIdx.x;
    if (i < N_NODES) cnt[i] = 1;  // self loop
}

__global__ void k_hist(const int* __restrict__ ei, int* cnt, int E) {
    int e = blockIdx.x * 256 + threadIdx.x;
    if (e < E) atomicAdd(&cnt[ei[E + e]], 1);
}

__global__ __launch_bounds__(1024) void k_scan(const int* __restrict__ cnt, int* off, int* cur) {
    __shared__ int part[1024];
    int t = threadIdx.x;
    const int per = (N_NODES + 1023) / 1024;
    int base = t * per;
    int sum = 0;
    for (int i = 0; i < per; ++i) { int idx = base + i; if (idx < N_NODES) sum += cnt[idx]; }
    part[t] = sum;
    __syncthreads();
    for (int s = 1; s < 1024; s <<= 1) {
        int v = (t >= s) ? part[t - s] : 0;
        __syncthreads();
        part[t] += v;
        __syncthreads();
    }
    int run = (t == 0) ? 0 : part[t - 1];
    for (int i = 0; i < per; ++i) {
        int idx = base + i;
        if (idx < N_NODES) { off[idx] = run; cur[idx] = run; run += cnt[idx]; }
    }
    if (t == 1023) off[N_NODES] = part[1023];
}

__global__ void k_fill_self(int* cur, int* srcl) {
    int i = blockIdx.x * 256 + threadIdx.x;
    if (i < N_NODES) { int p = atomicAdd(&cur[i], 1); srcl[p] = i; }
}

__global__ void k_fill_edge(const int* __restrict__ ei, int* cur, int* srcl, int E) {
    int e = blockIdx.x * 256 + threadIdx.x;
    if (e < E) { int d = ei[E + e]; int p = atomicAdd(&cur[d], 1); srcl[p] = ei[e]; }
}

// ---------------- conversions ----------------
__global__ void k_cvt(const float* __restrict__ in, unsigned short* __restrict__ outp, int n) {
    int i = blockIdx.x * 256 + threadIdx.x;
    if (i < n) outp[i] = f2bf(in[i]);
}

// W [K,320] f32 row-major -> Wt [320,K] bf16 (n-major, k contiguous)
__global__ void k_wt(const float* __restrict__ W, unsigned short* __restrict__ Wt, int K, int n) {
    int i = blockIdx.x * 256 + threadIdx.x;
    if (i < n) {
        int nn = i / K, k = i - nn * K;
        Wt[i] = f2bf(W[(size_t)k * HID + nn]);
    }
}

// ---------------- bf16 MFMA GEMM ----------------
// z==0 (GAT branch): Cbf (bf16 [M,320]) + fused s/d attention coefficients (f32, from
//                    pre-rounding accumulators; GN=64 == one head per column-block).
// z==1 (proj branch): C2 = A@Bt2 + bias2 (f32 [M,320]).
#define GM 128
#define GN 64
#define GK 64
#define GKP 72   // padded LDS stride: 144 B/row -> <=2-way bank conflicts (free)

__global__ __launch_bounds__(256) void k_gemm_mfma(
    const unsigned short* __restrict__ A,
    const unsigned short* __restrict__ Bt,
    unsigned short* __restrict__ Cbf,
    const float* __restrict__ a_s,   // [320] flat (head-major)
    const float* __restrict__ a_d,
    float* __restrict__ s_out,       // [M*5]
    float* __restrict__ d_out,
    const unsigned short* __restrict__ Bt2,
    const float* __restrict__ bias2,
    float* __restrict__ C2,
    int M, int K)
{
    const bool gat = (blockIdx.z == 0);
    const unsigned short* __restrict__ B = gat ? Bt : Bt2;
    __shared__ unsigned short As[GM][GKP];
    __shared__ unsigned short Bs[GN][GKP];
    __shared__ float sdred[2][GM][2];
    int tid = threadIdx.x;
    int lane = tid & 63, wid = tid >> 6;
    int wr = wid >> 1, wc = wid & 1;          // 2x2 wave grid
    int q = lane >> 4, r16 = lane & 15;
    int m0 = blockIdx.y * GM, n0 = blockIdx.x * GN;

    f32x4 acc[4][2];
#pragma unroll
    for (int mi = 0; mi < 4; ++mi)
#pragma unroll
        for (int ni = 0; ni < 2; ++ni)
#pragma unroll
            for (int r = 0; r < 4; ++r) acc[mi][ni][r] = 0.f;

    for (int k0 = 0; k0 < K; k0 += GK) {
#pragma unroll
        for (int i = 0; i < 4; ++i) {         // A tile 128x64
            int idx = tid + i * 256;
            int m = idx >> 3, g = idx & 7;
            int row = m0 + m;
            bf16x8 v;
            if (row < M) v = *(const bf16x8*)(A + (size_t)row * K + k0 + g * 8);
            else { for (int j = 0; j < 8; ++j) v[j] = 0; }
            *(bf16x8*)&As[m][g * 8] = v;
        }
#pragma unroll
        for (int i = 0; i < 2; ++i) {         // B tile 64x64 (transposed layout)
            int idx = tid + i * 256;
            int nn = idx >> 3, g = idx & 7;
            bf16x8 v = *(const bf16x8*)(B + (size_t)(n0 + nn) * K + k0 + g * 8);
            *(bf16x8*)&Bs[nn][g * 8] = v;
        }
        __syncthreads();
#pragma unroll
        for (int kc = 0; kc < 2; ++kc) {
            bf16x8 av[4], bv[2];
#pragma unroll
            for (int mi = 0; mi < 4; ++mi)
                av[mi] = *(const bf16x8*)&As[wr * 64 + mi * 16 + r16][kc * 32 + q * 8];
#pragma unroll
            for (int ni = 0; ni < 2; ++ni)
                bv[ni] = *(const bf16x8*)&Bs[wc * 32 + ni * 16 + r16][kc * 32 + q * 8];
#pragma unroll
            for (int mi = 0; mi < 4; ++mi)
#pragma unroll
                for (int ni = 0; ni < 2; ++ni)
                    acc[mi][ni] = __builtin_amdgcn_mfma_f32_16x16x32_bf16(av[mi], bv[ni], acc[mi][ni], 0, 0, 0);
        }
        __syncthreads();
    }

    if (gat) {
        // bf16 feature write + fused s/d reduction (deterministic, LDS cross-wave)
#pragma unroll
        for (int mi = 0; mi < 4; ++mi) {
#pragma unroll
            for (int ni = 0; ni < 2; ++ni) {
                int col = n0 + wc * 32 + ni * 16 + r16;
#pragma unroll
                for (int r = 0; r < 4; ++r) {
                    int row = m0 + wr * 64 + mi * 16 + q * 4 + r;
                    if (row < M) Cbf[(size_t)row * HID + col] = f2bf(acc[mi][ni][r]);
                }
            }
#pragma unroll
            for (int r = 0; r < 4; ++r) {
                float psum = 0.f, pdum = 0.f;
#pragma unroll
                for (int ni = 0; ni < 2; ++ni) {
                    int col = n0 + wc * 32 + ni * 16 + r16;
                    psum += acc[mi][ni][r] * a_s[col];
                    pdum += acc[mi][ni][r] * a_d[col];
                }
#pragma unroll
                for (int w = 8; w >= 1; w >>= 1) {
                    psum += __shfl_xor(psum, w, 64);
                    pdum += __shfl_xor(pdum, w, 64);
                }
                if (r16 == 0) {
                    int rl = wr * 64 + mi * 16 + q * 4 + r;
                    sdred[wc][rl][0] = psum;
                    sdred[wc][rl][1] = pdum;
                }
            }
        }
        __syncthreads();
        if (tid < GM) {
            int row = m0 + tid;
            if (row < M) {
                int head = blockIdx.x;
                s_out[(size_t)row * H_HEADS + head] = sdred[0][tid][0] + sdred[1][tid][0];
                d_out[(size_t)row * H_HEADS + head] = sdred[0][tid][1] + sdred[1][tid][1];
            }
        }
    } else {
#pragma unroll
        for (int mi = 0; mi < 4; ++mi)
#pragma unroll
            for (int ni = 0; ni < 2; ++ni) {
                int col = n0 + wc * 32 + ni * 16 + r16;
                float bval = bias2[col];
#pragma unroll
                for (int r = 0; r < 4; ++r) {
                    int row = m0 + wr * 64 + mi * 16 + q * 4 + r;
                    if (row < M) C2[(size_t)row * HID + col] = acc[mi][ni][r] + bval;
                }
            }
    }
}

// ---------------- GAT aggregation: edge-softmax + weighted bf16 gather, fused epilogue ----------------
// out[i] = base[i] + relu(agg_i/den + bias); writes f32 out + bf16 mirror (next layer GEMM A).
__global__ __launch_bounds__(256) void k_agg(const unsigned short* __restrict__ gatbf,
                                             const float* __restrict__ s,
                                             const float* __restrict__ dd,
                                             const int* __restrict__ off, const int* __restrict__ srcl,
                                             const float* __restrict__ bias, const float* __restrict__ base,
                                             float* __restrict__ outp, unsigned short* __restrict__ out_bf) {
    int wid = threadIdx.x >> 6;
    int lane = threadIdx.x & 63;
    int i = blockIdx.x * 4 + wid;
    if (i >= N_NODES) return;
    int o0 = off[i], o1 = off[i + 1];
    int deg = o1 - o0;

    float di[H_HEADS];
#pragma unroll
    for (int h = 0; h < H_HEADS; ++h) di[h] = dd[i * H_HEADS + h];

    // phase A: per-head max over edges
    float m[H_HEADS];
#pragma unroll
    for (int h = 0; h < H_HEADS; ++h) m[h] = -1e30f;
    for (int j = lane; j < deg; j += 64) {
        int sj = srcl[o0 + j];
#pragma unroll
        for (int h = 0; h < H_HEADS; ++h) {
            float e = s[sj * H_HEADS + h] + di[h];
            e = (e >= 0.f) ? e : 0.2f * e;
            m[h] = fmaxf(m[h], e);
        }
    }
#pragma unroll
    for (int w = 32; w >= 1; w >>= 1)
#pragma unroll
        for (int h = 0; h < H_HEADS; ++h) m[h] = fmaxf(m[h], __shfl_xor(m[h], w, 64));

    // phase B: exp, denominator, weighted bf16 gather
    float acc[H_HEADS] = {0.f, 0.f, 0.f, 0.f, 0.f};
    float den[H_HEADS] = {0.f, 0.f, 0.f, 0.f, 0.f};
    for (int cb = 0; cb < deg; cb += 64) {
        int j = cb + lane;
        int sj = 0;
        float exl[H_HEADS] = {0.f, 0.f, 0.f, 0.f, 0.f};
        if (j < deg) {
            sj = srcl[o0 + j];
#pragma unroll
            for (int h = 0; h < H_HEADS; ++h) {
                float e = s[sj * H_HEADS + h] + di[h];
                e = (e >= 0.f) ? e : 0.2f * e;
                float ex = __expf(e - m[h]);
                exl[h] = ex;
                den[h] += ex;
            }
        }
        int cnt = min(64, deg - cb);
        for (int jj = 0; jj < cnt; ++jj) {
            int sjj = __shfl(sj, jj, 64);
            const unsigned short* row = gatbf + (size_t)sjj * HID;
            float w0 = __shfl(exl[0], jj, 64);
            float w1 = __shfl(exl[1], jj, 64);
            float w2 = __shfl(exl[2], jj, 64);
            float w3 = __shfl(exl[3], jj, 64);
            float w4 = __shfl(exl[4], jj, 64);
            acc[0] += w0 * bf2f(row[0 * 64 + lane]);
            acc[1] += w1 * bf2f(row[1 * 64 + lane]);
            acc[2] += w2 * bf2f(row[2 * 64 + lane]);
            acc[3] += w3 * bf2f(row[3 * 64 + lane]);
            acc[4] += w4 * bf2f(row[4 * 64 + lane]);
        }
    }
#pragma unroll
    for (int w = 32; w >= 1; w >>= 1)
#pragma unroll
        for (int h = 0; h < H_HEADS; ++h) den[h] += __shfl_xor(den[h], w, 64);

#pragma unroll
    for (int h = 0; h < H_HEADS; ++h) {
        int col = h * 64 + lane;
        float v = acc[h] / den[h] + bias[col];
        v = fmaxf(v, 0.f);
        float outv = base[(size_t)i * HID + col] + v;
        outp[(size_t)i * HID + col] = outv;
        out_bf[(size_t)i * HID + col] = f2bf(outv);
    }
}

// ---------------- pooling: segment mean over sorted batch ----------------
__global__ __launch_bounds__(320) void k_pool(const float* __restrict__ h, const int* __restrict__ batch,
                                              float* __restrict__ pooled) {
    int g = blockIdx.x;
    int t = threadIdx.x;  // 320
    int lo = 0, hi = N_NODES;
    while (lo < hi) { int mid = (lo + hi) >> 1; if (batch[mid] < g) lo = mid + 1; else hi = mid; }
    int start = lo;
    hi = N_NODES;
    while (lo < hi) { int mid = (lo + hi) >> 1; if (batch[mid] < g + 1) lo = mid + 1; else hi = mid; }
    int end = lo;
    float acc = 0.f;
    for (int r = start; r < end; ++r) acc += h[(size_t)r * HID + t];
    float cntf = (float)(end - start);
    pooled[g * HID + t] = acc / fmaxf(cntf, 1.f);
}

// ---------------- MLP head ----------------
__global__ __launch_bounds__(64) void k_mlp1(const float* __restrict__ pooled, const float* __restrict__ W,
                                             const float* __restrict__ b, float* __restrict__ z1) {
    int r = blockIdx.x;
    int col = blockIdx.y * 64 + threadIdx.x;
    float acc = 0.f;
    for (int k = 0; k < HID; ++k) acc += pooled[r * HID + k] * W[k * NHID + col];
    acc += b[col];
    z1[r * NHID + col] = fmaxf(acc, 0.f);
}

__global__ __launch_bounds__(256) void k_mlp2_ln(const float* __restrict__ z1, const float* __restrict__ W,
                                                 const float* __restrict__ b, const float* __restrict__ g_,
                                                 const float* __restrict__ beta, float* __restrict__ outp) {
    int r = blockIdx.x;
    int col = threadIdx.x;  // 256
    float acc = 0.f;
    for (int k = 0; k < NHID; ++k) acc += z1[r * NHID + k] * W[k * NOUT + col];
    acc += b[col];
    __shared__ float red[256];
    red[col] = acc;
    __syncthreads();
    for (int s = 128; s > 0; s >>= 1) { if (col < s) red[col] += red[col + s]; __syncthreads(); }
    float mu = red[0] / (float)NOUT;
    __syncthreads();
    float dv = acc - mu;
    red[col] = dv * dv;
    __syncthreads();
    for (int s = 128; s > 0; s >>= 1) { if (col < s) red[col] += red[col + s]; __syncthreads(); }
    float var = red[0] / (float)NOUT;
    outp[r * NOUT + col] = g_[col] * dv * rsqrtf(var + 1e-5f) + beta[col];
}

// ---------------- launch ----------------
extern "C" void kernel_launch(void* const* d_in, const int* in_sizes, int n_in,
                              void* d_out, int out_size, void* d_ws, size_t ws_size,
                              hipStream_t stream) {
    const float* x     = (const float*)d_in[0];
    const int*   ei    = (const int*)d_in[1];
    const int*   batch = (const int*)d_in[2];
    const float *W[5], *as_[5], *ad_[5], *bb[5];
    int idx = 3;
    for (int l = 0; l < 5; ++l) {
        W[l]   = (const float*)d_in[idx++];
        as_[l] = (const float*)d_in[idx++];
        ad_[l] = (const float*)d_in[idx++];
        bb[l]  = (const float*)d_in[idx++];
    }
    const float* Wm1 = (const float*)d_in[idx++];
    const float* bm1 = (const float*)d_in[idx++];
    const float* Wm2 = (const float*)d_in[idx++];
    const float* bm2 = (const float*)d_in[idx++];
    const float* Wh1 = (const float*)d_in[idx++];
    const float* bh1 = (const float*)d_in[idx++];
    const float* Wh2 = (const float*)d_in[idx++];
    const float* bh2 = (const float*)d_in[idx++];
    const float* lng = (const float*)d_in[idx++];
    const float* lnb = (const float*)d_in[idx++];

    const int E = in_sizes[1] / 2;
    float* out = (float*)d_out;

    char* ws = (char*)d_ws;
    size_t o = 0;
    auto alloc = [&](size_t bytes) -> char* {
        char* p = ws + o;
        o += bytes;
        o = (o + 255) & ~(size_t)255;
        return p;
    };
    const size_t NB = (size_t)N_NODES * HID * sizeof(float);
    float* big1   = (float*)alloc(NB);
    float* big2   = (float*)alloc(NB);
    float* sbuf   = (float*)alloc((size_t)N_NODES * H_HEADS * sizeof(float));
    float* dbuf   = (float*)alloc((size_t)N_NODES * H_HEADS * sizeof(float));
    int*   cnt    = (int*)alloc((size_t)N_NODES * sizeof(int));
    int*   off    = (int*)alloc((size_t)(N_NODES + 1) * sizeof(int));
    int*   cur    = (int*)alloc((size_t)N_NODES * sizeof(int));
    int*   srcl   = (int*)alloc((size_t)(E + N_NODES) * sizeof(int));
    float* pooled = (float*)alloc((size_t)G_GRAPHS * HID * sizeof(float));
    float* z1     = (float*)alloc((size_t)G_GRAPHS * NHID * sizeof(float));
    unsigned short* x_bf   = (unsigned short*)alloc((size_t)N_NODES * F_IN * sizeof(short));
    unsigned short* h_bf   = (unsigned short*)alloc((size_t)N_NODES * HID * sizeof(short));
    unsigned short* gat_bf = (unsigned short*)alloc((size_t)N_NODES * HID * sizeof(short));
    unsigned short* Wt1  = (unsigned short*)alloc((size_t)HID * F_IN * sizeof(short));
    unsigned short* Wtm1 = (unsigned short*)alloc((size_t)HID * F_IN * sizeof(short));
    unsigned short* Wt2  = (unsigned short*)alloc((size_t)HID * HID * sizeof(short));
    unsigned short* Wtm2 = (unsigned short*)alloc((size_t)HID * HID * sizeof(short));
    unsigned short* Wt3  = (unsigned short*)alloc((size_t)HID * HID * sizeof(short));
    unsigned short* Wt4  = (unsigned short*)alloc((size_t)HID * HID * sizeof(short));
    unsigned short* Wt5  = (unsigned short*)alloc((size_t)HID * HID * sizeof(short));

    // CSR
    k_init_cnt<<<(N_NODES + 255) / 256, 256, 0, stream>>>(cnt);
    k_hist<<<(E + 255) / 256, 256, 0, stream>>>(ei, cnt, E);
    k_scan<<<1, 1024, 0, stream>>>(cnt, off, cur);
    k_fill_self<<<(N_NODES + 255) / 256, 256, 0, stream>>>(cur, srcl);
    k_fill_edge<<<(E + 255) / 256, 256, 0, stream>>>(ei, cur, srcl, E);

    // conversions
    {
        int n = N_NODES * F_IN;
        k_cvt<<<(n + 255) / 256, 256, 0, stream>>>(x, x_bf, n);
        int nw_small = HID * F_IN;
        int nw_big = HID * HID;
        k_wt<<<(nw_small + 255) / 256, 256, 0, stream>>>(W[0], Wt1, F_IN, nw_small);
        k_wt<<<(nw_small + 255) / 256, 256, 0, stream>>>(Wm1, Wtm1, F_IN, nw_small);
        k_wt<<<(nw_big + 255) / 256, 256, 0, stream>>>(W[1], Wt2, HID, nw_big);
        k_wt<<<(nw_big + 255) / 256, 256, 0, stream>>>(Wm2, Wtm2, HID, nw_big);
        k_wt<<<(nw_big + 255) / 256, 256, 0, stream>>>(W[2], Wt3, HID, nw_big);
        k_wt<<<(nw_big + 255) / 256, 256, 0, stream>>>(W[3], Wt4, HID, nw_big);
        k_wt<<<(nw_big + 255) / 256, 256, 0, stream>>>(W[4], Wt5, HID, nw_big);
    }

    dim3 gemm_grid2(HID / GN, (N_NODES + GM - 1) / GM, 2);
    dim3 gemm_grid1(HID / GN, (N_NODES + GM - 1) / GM, 1);
    dim3 agg_grid((N_NODES + 3) / 4);

    // Layer 1: z0: gat_bf/s/d = x@W1 ; z1: big1 = x@Wm1+bm1 ; agg -> big1, h_bf
    k_gemm_mfma<<<gemm_grid2, 256, 0, stream>>>(x_bf, Wt1, gat_bf, as_[0], ad_[0], sbuf, dbuf,
                                                Wtm1, bm1, big1, N_NODES, F_IN);
    k_agg<<<agg_grid, 256, 0, stream>>>(gat_bf, sbuf, dbuf, off, srcl, bb[0], big1, big1, h_bf);

    // Layer 2: z0: gat_bf/s/d = h@W2 ; z1: big2 = h@Wm2+bm2 ; agg -> big2, h_bf
    k_gemm_mfma<<<gemm_grid2, 256, 0, stream>>>(h_bf, Wt2, gat_bf, as_[1], ad_[1], sbuf, dbuf,
                                                Wtm2, bm2, big2, N_NODES, HID);
    k_agg<<<agg_grid, 256, 0, stream>>>(gat_bf, sbuf, dbuf, off, srcl, bb[1], big2, big2, h_bf);

    // Layers 3-5: h = h + relu(gat(h)) in place on big2
    const unsigned short* Wtl[3] = {Wt3, Wt4, Wt5};
    for (int l = 2; l < 5; ++l) {
        k_gemm_mfma<<<gemm_grid1, 256, 0, stream>>>(h_bf, Wtl[l - 2], gat_bf, as_[l], ad_[l], sbuf, dbuf,
                                                    nullptr, nullptr, nullptr, N_NODES, HID);
        k_agg<<<agg_grid, 256, 0, stream>>>(gat_bf, sbuf, dbuf, off, srcl, bb[l], big2, big2, h_bf);
    }

    // pool + head
    k_pool<<<G_GRAPHS, HID, 0, stream>>>(big2, batch, pooled);
    k_mlp1<<<dim3(G_GRAPHS, NHID / 64), 64, 0, stream>>>(pooled, Wh1, bh1, z1);
    k_mlp2_ln<<<G_GRAPHS, NOUT, 0, stream>>>(z1, Wh2, bh2, lng, lnb, out);
}

// Round 4
// 515.301 us; speedup vs baseline: 2.1271x; 1.0221x over previous
//
#include <hip/hip_runtime.h>
#include <math.h>

#define N_NODES 20000
#define F_IN    128
#define H_HEADS 5
#define HID     320
#define NHID    512
#define NOUT    256
#define G_GRAPHS 200

typedef __attribute__((ext_vector_type(8))) short bf16x8;
typedef __attribute__((ext_vector_type(4))) float f32x4;
typedef __attribute__((ext_vector_type(2))) unsigned short u16x2;

__device__ __forceinline__ unsigned short f2bf(float f) {
    unsigned int u = __float_as_uint(f);
    u += 0x7fffu + ((u >> 16) & 1u);
    return (unsigned short)(u >> 16);
}
__device__ __forceinline__ float bf2f(unsigned short u) {
    return __uint_as_float(((unsigned int)u) << 16);
}

// ---------------- CSR build (dst -> list of src), self-loops included ----------------
__global__ void k_init_cnt(int* cnt) {
    int i = blockIdx.x * 256 + threadIdx.x;
    if (i < N_NODES) cnt[i] = 1;  // self loop
}

__global__ void k_hist(const int* __restrict__ ei, int* cnt, int E) {
    int e = blockIdx.x * 256 + threadIdx.x;
    if (e < E) atomicAdd(&cnt[ei[E + e]], 1);
}

__global__ __launch_bounds__(1024) void k_scan(const int* __restrict__ cnt, int* off, int* cur) {
    __shared__ int part[1024];
    int t = threadIdx.x;
    const int per = (N_NODES + 1023) / 1024;
    int base = t * per;
    int sum = 0;
    for (int i = 0; i < per; ++i) { int idx = base + i; if (idx < N_NODES) sum += cnt[idx]; }
    part[t] = sum;
    __syncthreads();
    for (int s = 1; s < 1024; s <<= 1) {
        int v = (t >= s) ? part[t - s] : 0;
        __syncthreads();
        part[t] += v;
        __syncthreads();
    }
    int run = (t == 0) ? 0 : part[t - 1];
    for (int i = 0; i < per; ++i) {
        int idx = base + i;
        if (idx < N_NODES) { off[idx] = run; cur[idx] = run; run += cnt[idx]; }
    }
    if (t == 1023) off[N_NODES] = part[1023];
}

__global__ void k_fill_self(int* cur, int* srcl) {
    int i = blockIdx.x * 256 + threadIdx.x;
    if (i < N_NODES) { int p = atomicAdd(&cur[i], 1); srcl[p] = i; }
}

__global__ void k_fill_edge(const int* __restrict__ ei, int* cur, int* srcl, int E) {
    int e = blockIdx.x * 256 + threadIdx.x;
    if (e < E) { int d = ei[E + e]; int p = atomicAdd(&cur[d], 1); srcl[p] = ei[e]; }
}

// ---------------- conversions ----------------
__global__ void k_cvt(const float* __restrict__ in, unsigned short* __restrict__ outp, int n) {
    int i = blockIdx.x * 256 + threadIdx.x;
    if (i < n) outp[i] = f2bf(in[i]);
}

// W [K,320] f32 row-major -> Wt [320,K] bf16 (n-major, k contiguous)
__global__ void k_wt(const float* __restrict__ W, unsigned short* __restrict__ Wt, int K, int n) {
    int i = blockIdx.x * 256 + threadIdx.x;
    if (i < n) {
        int nn = i / K, k = i - nn * K;
        Wt[i] = f2bf(W[(size_t)k * HID + nn]);
    }
}

// ---------------- bf16 MFMA GEMM, full-width 64x320 blocks ----------------
// z==0 (GAT): Cbf bf16 [M,320] + packed sd[row*16 +h]=s, [+8+h]=d from f32 accumulators.
// z==1 (proj): C2 = A@Bt2 + bias2 (f32).
#define QM  64
#define GKP 72   // padded LDS stride (144 B/row -> 2-way max, free)

__global__ __launch_bounds__(512) void k_gemm2(
    const unsigned short* __restrict__ A,
    const unsigned short* __restrict__ Bt,
    unsigned short* __restrict__ Cbf,
    const float* __restrict__ a_s,
    const float* __restrict__ a_d,
    float* __restrict__ sd_out,
    const unsigned short* __restrict__ Bt2,
    const float* __restrict__ bias2,
    float* __restrict__ C2,
    int M, int K)
{
    const bool gat = (blockIdx.z == 0);
    const unsigned short* __restrict__ B = gat ? Bt : Bt2;
    __shared__ unsigned short As[QM][GKP];
    __shared__ unsigned short Bs[HID][GKP];
    __shared__ float sdred[4][2][QM][2];
    int tid = threadIdx.x;
    int lane = tid & 63, wid = tid >> 6;
    int wr = wid >> 2, wc = wid & 3;      // 2 (rows) x 4 (cols) wave grid
    int q = lane >> 4, r16 = lane & 15;
    int m0 = blockIdx.x * QM;

    f32x4 acc[2][5];
#pragma unroll
    for (int mi = 0; mi < 2; ++mi)
#pragma unroll
        for (int ni = 0; ni < 5; ++ni)
#pragma unroll
            for (int r = 0; r < 4; ++r) acc[mi][ni][r] = 0.f;

    for (int k0 = 0; k0 < K; k0 += 64) {
        {   // A tile 64x64: one bf16x8 per thread
            int m = tid >> 3, g = tid & 7;
            int row = m0 + m;
            bf16x8 v;
            if (row < M) v = *(const bf16x8*)(A + (size_t)row * K + k0 + g * 8);
            else { for (int j = 0; j < 8; ++j) v[j] = 0; }
            *(bf16x8*)&As[m][g * 8] = v;
        }
#pragma unroll
        for (int i = 0; i < 5; ++i) {     // B tile 320x64: five bf16x8 per thread
            int idx = tid + i * 512;
            int nn = idx >> 3, g = idx & 7;
            *(bf16x8*)&Bs[nn][g * 8] = *(const bf16x8*)(B + (size_t)nn * K + k0 + g * 8);
        }
        __syncthreads();
#pragma unroll
        for (int kc = 0; kc < 2; ++kc) {
            bf16x8 av[2], bv[5];
#pragma unroll
            for (int mi = 0; mi < 2; ++mi)
                av[mi] = *(const bf16x8*)&As[wr * 32 + mi * 16 + r16][kc * 32 + q * 8];
#pragma unroll
            for (int ni = 0; ni < 5; ++ni)
                bv[ni] = *(const bf16x8*)&Bs[wc * 80 + ni * 16 + r16][kc * 32 + q * 8];
#pragma unroll
            for (int mi = 0; mi < 2; ++mi)
#pragma unroll
                for (int ni = 0; ni < 5; ++ni)
                    acc[mi][ni] = __builtin_amdgcn_mfma_f32_16x16x32_bf16(av[mi], bv[ni], acc[mi][ni], 0, 0, 0);
        }
        __syncthreads();
    }

    if (gat) {
#pragma unroll
        for (int mi = 0; mi < 2; ++mi)
#pragma unroll
            for (int ni = 0; ni < 5; ++ni) {
                int col = wc * 80 + ni * 16 + r16;
#pragma unroll
                for (int r = 0; r < 4; ++r) {
                    int row = m0 + wr * 32 + mi * 16 + q * 4 + r;
                    if (row < M) Cbf[(size_t)row * HID + col] = f2bf(acc[mi][ni][r]);
                }
            }
        // per-head s/d partials: each 16-wide frag lies in one head; wave covers 2 heads
        int headA = (5 * wc) >> 2;
#pragma unroll
        for (int mi = 0; mi < 2; ++mi)
#pragma unroll
            for (int r = 0; r < 4; ++r) {
                float psA = 0.f, pdA = 0.f, psB = 0.f, pdB = 0.f;
#pragma unroll
                for (int ni = 0; ni < 5; ++ni) {
                    int col = wc * 80 + ni * 16 + r16;
                    int hf = (5 * wc + ni) >> 2;
                    float v = acc[mi][ni][r];
                    float ps = v * a_s[col], pd = v * a_d[col];
                    if (hf == headA) { psA += ps; pdA += pd; }
                    else             { psB += ps; pdB += pd; }
                }
#pragma unroll
                for (int w = 8; w >= 1; w >>= 1) {
                    psA += __shfl_xor(psA, w, 64);
                    pdA += __shfl_xor(pdA, w, 64);
                    psB += __shfl_xor(psB, w, 64);
                    pdB += __shfl_xor(pdB, w, 64);
                }
                if (r16 == 0) {
                    int rl = wr * 32 + mi * 16 + q * 4 + r;
                    sdred[wc][0][rl][0] = psA; sdred[wc][0][rl][1] = pdA;
                    sdred[wc][1][rl][0] = psB; sdred[wc][1][rl][1] = pdB;
                }
            }
        __syncthreads();
        if (tid < QM) {
            int row = m0 + tid;
            if (row < M) {
                float s0 = sdred[0][0][tid][0];
                float s1 = sdred[0][1][tid][0] + sdred[1][0][tid][0];
                float s2 = sdred[1][1][tid][0] + sdred[2][0][tid][0];
                float s3 = sdred[2][1][tid][0] + sdred[3][0][tid][0];
                float s4 = sdred[3][1][tid][0];
                float d0 = sdred[0][0][tid][1];
                float d1 = sdred[0][1][tid][1] + sdred[1][0][tid][1];
                float d2 = sdred[1][1][tid][1] + sdred[2][0][tid][1];
                float d3 = sdred[2][1][tid][1] + sdred[3][0][tid][1];
                float d4 = sdred[3][1][tid][1];
                size_t sb = (size_t)row * 16;
                sd_out[sb + 0] = s0; sd_out[sb + 1] = s1; sd_out[sb + 2] = s2;
                sd_out[sb + 3] = s3; sd_out[sb + 4] = s4;
                sd_out[sb + 8] = d0; sd_out[sb + 9] = d1; sd_out[sb + 10] = d2;
                sd_out[sb + 11] = d3; sd_out[sb + 12] = d4;
            }
        }
    } else {
#pragma unroll
        for (int mi = 0; mi < 2; ++mi)
#pragma unroll
            for (int ni = 0; ni < 5; ++ni) {
                int col = wc * 80 + ni * 16 + r16;
                float bval = bias2[col];
#pragma unroll
                for (int r = 0; r < 4; ++r) {
                    int row = m0 + wr * 32 + mi * 16 + q * 4 + r;
                    if (row < M) C2[(size_t)row * HID + col] = acc[mi][ni][r] + bval;
                }
            }
    }
}

// ---------------- GAT aggregation: single-pass online softmax + weighted bf16 gather ----------------
// out[i] = base[i] + relu(agg_i/den + bias); writes f32 out + bf16 mirror.
// Lane layout: lane holds cols {2l,2l+1}(seg0), {128+2l,128+2l+1}(seg1), {256+l}(seg2).
__global__ __launch_bounds__(256) void k_agg(const unsigned short* __restrict__ gatbf,
                                             const float* __restrict__ sd,
                                             const int* __restrict__ off, const int* __restrict__ srcl,
                                             const float* __restrict__ bias, const float* __restrict__ base,
                                             float* __restrict__ outp, unsigned short* __restrict__ out_bf) {
    int wid = threadIdx.x >> 6;
    int lane = threadIdx.x & 63;
    int i = blockIdx.x * 4 + wid;
    if (i >= N_NODES) return;
    int oS = off[i], oE = off[i + 1];
    int deg = oE - oS;
    const bool lo32 = (lane < 32);

    const float4 dv = *(const float4*)&sd[(size_t)i * 16 + 8];
    const float di4v = sd[(size_t)i * 16 + 12];
    float di[5] = {dv.x, dv.y, dv.z, dv.w, di4v};

    float m[5], den[5] = {0.f, 0.f, 0.f, 0.f, 0.f};
#pragma unroll
    for (int h = 0; h < 5; ++h) m[h] = -1e30f;
    float a0x = 0.f, a0y = 0.f, a1x = 0.f, a1y = 0.f, a2 = 0.f;

    for (int cb = 0; cb < deg; cb += 64) {
        int j = cb + lane;
        bool act = (j < deg);
        int sj = act ? srcl[oS + j] : 0;
        float e[5];
        if (act) {
            const float4 sv = *(const float4*)&sd[(size_t)sj * 16];
            float s4 = sd[(size_t)sj * 16 + 4];
            float es0 = sv.x + di[0], es1 = sv.y + di[1], es2 = sv.z + di[2];
            float es3 = sv.w + di[3], es4 = s4 + di[4];
            e[0] = (es0 >= 0.f) ? es0 : 0.2f * es0;
            e[1] = (es1 >= 0.f) ? es1 : 0.2f * es1;
            e[2] = (es2 >= 0.f) ? es2 : 0.2f * es2;
            e[3] = (es3 >= 0.f) ? es3 : 0.2f * es3;
            e[4] = (es4 >= 0.f) ? es4 : 0.2f * es4;
        } else {
#pragma unroll
            for (int h = 0; h < 5; ++h) e[h] = -1e30f;
        }
        float cm[5];
#pragma unroll
        for (int h = 0; h < 5; ++h) cm[h] = e[h];
#pragma unroll
        for (int w = 32; w >= 1; w >>= 1)
#pragma unroll
            for (int h = 0; h < 5; ++h) cm[h] = fmaxf(cm[h], __shfl_xor(cm[h], w, 64));
        if (cb) {  // rescale path (deg>64) — rare, kept for correctness
            float r[5];
#pragma unroll
            for (int h = 0; h < 5; ++h) {
                float nm = fmaxf(m[h], cm[h]);
                r[h] = __expf(m[h] - nm);
                m[h] = nm;
                den[h] *= r[h];
            }
            float rA = lo32 ? r[0] : r[1], rB = lo32 ? r[2] : r[3];
            a0x *= rA; a0y *= rA; a1x *= rB; a1y *= rB; a2 *= r[4];
        } else {
#pragma unroll
            for (int h = 0; h < 5; ++h) m[h] = cm[h];
        }
        float ex[5];
#pragma unroll
        for (int h = 0; h < 5; ++h) {
            ex[h] = act ? __expf(e[h] - m[h]) : 0.f;
            den[h] += ex[h];
        }
        int cnt = min(64, deg - cb);
        for (int jj = 0; jj < cnt; ++jj) {
            int sjj = __shfl(sj, jj, 64);
            float w0 = __shfl(ex[0], jj, 64);
            float w1 = __shfl(ex[1], jj, 64);
            float w2 = __shfl(ex[2], jj, 64);
            float w3 = __shfl(ex[3], jj, 64);
            float w4 = __shfl(ex[4], jj, 64);
            const unsigned short* row = gatbf + (size_t)sjj * HID;
            u16x2 p0 = *(const u16x2*)(row + 2 * lane);
            u16x2 p1 = *(const u16x2*)(row + 128 + 2 * lane);
            unsigned short p2 = row[256 + lane];
            float wA = lo32 ? w0 : w1, wB = lo32 ? w2 : w3;
            a0x += wA * bf2f(p0[0]);
            a0y += wA * bf2f(p0[1]);
            a1x += wB * bf2f(p1[0]);
            a1y += wB * bf2f(p1[1]);
            a2 += w4 * bf2f(p2);
        }
    }
#pragma unroll
    for (int w = 32; w >= 1; w >>= 1)
#pragma unroll
        for (int h = 0; h < 5; ++h) den[h] += __shfl_xor(den[h], w, 64);

    float dA = lo32 ? den[0] : den[1], dB = lo32 ? den[2] : den[3];
    int c0 = 2 * lane, c1 = 128 + 2 * lane, c2 = 256 + lane;
    size_t rb = (size_t)i * HID;
    float2 bi0 = *(const float2*)&bias[c0];
    float2 bi1 = *(const float2*)&bias[c1];
    float  bi2 = bias[c2];
    float2 ba0 = *(const float2*)&base[rb + c0];
    float2 ba1 = *(const float2*)&base[rb + c1];
    float  ba2 = base[rb + c2];
    float2 o0v, o1v;
    o0v.x = ba0.x + fmaxf(a0x / dA + bi0.x, 0.f);
    o0v.y = ba0.y + fmaxf(a0y / dA + bi0.y, 0.f);
    o1v.x = ba1.x + fmaxf(a1x / dB + bi1.x, 0.f);
    o1v.y = ba1.y + fmaxf(a1y / dB + bi1.y, 0.f);
    float o2v = ba2 + fmaxf(a2 / den[4] + bi2, 0.f);
    *(float2*)&outp[rb + c0] = o0v;
    *(float2*)&outp[rb + c1] = o1v;
    outp[rb + c2] = o2v;
    u16x2 q0, q1;
    q0[0] = f2bf(o0v.x); q0[1] = f2bf(o0v.y);
    q1[0] = f2bf(o1v.x); q1[1] = f2bf(o1v.y);
    *(u16x2*)&out_bf[rb + c0] = q0;
    *(u16x2*)&out_bf[rb + c1] = q1;
    out_bf[rb + c2] = f2bf(o2v);
}

// ---------------- pooling: segment mean over sorted batch ----------------
__global__ __launch_bounds__(320) void k_pool(const float* __restrict__ h, const int* __restrict__ batch,
                                              float* __restrict__ pooled) {
    int g = blockIdx.x;
    int t = threadIdx.x;  // 320
    int lo = 0, hi = N_NODES;
    while (lo < hi) { int mid = (lo + hi) >> 1; if (batch[mid] < g) lo = mid + 1; else hi = mid; }
    int start = lo;
    hi = N_NODES;
    while (lo < hi) { int mid = (lo + hi) >> 1; if (batch[mid] < g + 1) lo = mid + 1; else hi = mid; }
    int end = lo;
    float acc = 0.f;
    for (int r = start; r < end; ++r) acc += h[(size_t)r * HID + t];
    float cntf = (float)(end - start);
    pooled[g * HID + t] = acc / fmaxf(cntf, 1.f);
}

// ---------------- MLP head ----------------
__global__ __launch_bounds__(64) void k_mlp1(const float* __restrict__ pooled, const float* __restrict__ W,
                                             const float* __restrict__ b, float* __restrict__ z1) {
    int r = blockIdx.x;
    int col = blockIdx.y * 64 + threadIdx.x;
    float acc = 0.f;
    for (int k = 0; k < HID; ++k) acc += pooled[r * HID + k] * W[k * NHID + col];
    acc += b[col];
    z1[r * NHID + col] = fmaxf(acc, 0.f);
}

__global__ __launch_bounds__(256) void k_mlp2_ln(const float* __restrict__ z1, const float* __restrict__ W,
                                                 const float* __restrict__ b, const float* __restrict__ g_,
                                                 const float* __restrict__ beta, float* __restrict__ outp) {
    int r = blockIdx.x;
    int col = threadIdx.x;  // 256
    float acc = 0.f;
    for (int k = 0; k < NHID; ++k) acc += z1[r * NHID + k] * W[k * NOUT + col];
    acc += b[col];
    __shared__ float red[256];
    red[col] = acc;
    __syncthreads();
    for (int s = 128; s > 0; s >>= 1) { if (col < s) red[col] += red[col + s]; __syncthreads(); }
    float mu = red[0] / (float)NOUT;
    __syncthreads();
    float dv = acc - mu;
    red[col] = dv * dv;
    __syncthreads();
    for (int s = 128; s > 0; s >>= 1) { if (col < s) red[col] += red[col + s]; __syncthreads(); }
    float var = red[0] / (float)NOUT;
    outp[r * NOUT + col] = g_[col] * dv * rsqrtf(var + 1e-5f) + beta[col];
}

// ---------------- launch ----------------
extern "C" void kernel_launch(void* const* d_in, const int* in_sizes, int n_in,
                              void* d_out, int out_size, void* d_ws, size_t ws_size,
                              hipStream_t stream) {
    const float* x     = (const float*)d_in[0];
    const int*   ei    = (const int*)d_in[1];
    const int*   batch = (const int*)d_in[2];
    const float *W[5], *as_[5], *ad_[5], *bb[5];
    int idx = 3;
    for (int l = 0; l < 5; ++l) {
        W[l]   = (const float*)d_in[idx++];
        as_[l] = (const float*)d_in[idx++];
        ad_[l] = (const float*)d_in[idx++];
        bb[l]  = (const float*)d_in[idx++];
    }
    const float* Wm1 = (const float*)d_in[idx++];
    const float* bm1 = (const float*)d_in[idx++];
    const float* Wm2 = (const float*)d_in[idx++];
    const float* bm2 = (const float*)d_in[idx++];
    const float* Wh1 = (const float*)d_in[idx++];
    const float* bh1 = (const float*)d_in[idx++];
    const float* Wh2 = (const float*)d_in[idx++];
    const float* bh2 = (const float*)d_in[idx++];
    const float* lng = (const float*)d_in[idx++];
    const float* lnb = (const float*)d_in[idx++];

    const int E = in_sizes[1] / 2;
    float* out = (float*)d_out;

    char* ws = (char*)d_ws;
    size_t o = 0;
    auto alloc = [&](size_t bytes) -> char* {
        char* p = ws + o;
        o += bytes;
        o = (o + 255) & ~(size_t)255;
        return p;
    };
    const size_t NB = (size_t)N_NODES * HID * sizeof(float);
    float* big1   = (float*)alloc(NB);
    float* big2   = (float*)alloc(NB);
    float* sdbuf  = (float*)alloc((size_t)N_NODES * 16 * sizeof(float));
    int*   cnt    = (int*)alloc((size_t)N_NODES * sizeof(int));
    int*   off    = (int*)alloc((size_t)(N_NODES + 1) * sizeof(int));
    int*   cur    = (int*)alloc((size_t)N_NODES * sizeof(int));
    int*   srcl   = (int*)alloc((size_t)(E + N_NODES) * sizeof(int));
    float* pooled = (float*)alloc((size_t)G_GRAPHS * HID * sizeof(float));
    float* z1     = (float*)alloc((size_t)G_GRAPHS * NHID * sizeof(float));
    unsigned short* x_bf   = (unsigned short*)alloc((size_t)N_NODES * F_IN * sizeof(short));
    unsigned short* h_bf   = (unsigned short*)alloc((size_t)N_NODES * HID * sizeof(short));
    unsigned short* gat_bf = (unsigned short*)alloc((size_t)N_NODES * HID * sizeof(short));
    unsigned short* Wt1  = (unsigned short*)alloc((size_t)HID * F_IN * sizeof(short));
    unsigned short* Wtm1 = (unsigned short*)alloc((size_t)HID * F_IN * sizeof(short));
    unsigned short* Wt2  = (unsigned short*)alloc((size_t)HID * HID * sizeof(short));
    unsigned short* Wtm2 = (unsigned short*)alloc((size_t)HID * HID * sizeof(short));
    unsigned short* Wt3  = (unsigned short*)alloc((size_t)HID * HID * sizeof(short));
    unsigned short* Wt4  = (unsigned short*)alloc((size_t)HID * HID * sizeof(short));
    unsigned short* Wt5  = (unsigned short*)alloc((size_t)HID * HID * sizeof(short));

    // CSR
    k_init_cnt<<<(N_NODES + 255) / 256, 256, 0, stream>>>(cnt);
    k_hist<<<(E + 255) / 256, 256, 0, stream>>>(ei, cnt, E);
    k_scan<<<1, 1024, 0, stream>>>(cnt, off, cur);
    k_fill_self<<<(N_NODES + 255) / 256, 256, 0, stream>>>(cur, srcl);
    k_fill_edge<<<(E + 255) / 256, 256, 0, stream>>>(ei, cur, srcl, E);

    // conversions
    {
        int n = N_NODES * F_IN;
        k_cvt<<<(n + 255) / 256, 256, 0, stream>>>(x, x_bf, n);
        int nw_small = HID * F_IN;
        int nw_big = HID * HID;
        k_wt<<<(nw_small + 255) / 256, 256, 0, stream>>>(W[0], Wt1, F_IN, nw_small);
        k_wt<<<(nw_small + 255) / 256, 256, 0, stream>>>(Wm1, Wtm1, F_IN, nw_small);
        k_wt<<<(nw_big + 255) / 256, 256, 0, stream>>>(W[1], Wt2, HID, nw_big);
        k_wt<<<(nw_big + 255) / 256, 256, 0, stream>>>(Wm2, Wtm2, HID, nw_big);
        k_wt<<<(nw_big + 255) / 256, 256, 0, stream>>>(W[2], Wt3, HID, nw_big);
        k_wt<<<(nw_big + 255) / 256, 256, 0, stream>>>(W[3], Wt4, HID, nw_big);
        k_wt<<<(nw_big + 255) / 256, 256, 0, stream>>>(W[4], Wt5, HID, nw_big);
    }

    const int MB = (N_NODES + QM - 1) / QM;  // 313
    dim3 gg2(MB, 1, 2);
    dim3 gg1(MB, 1, 1);
    dim3 agg_grid((N_NODES + 3) / 4);

    // Layer 1: z0: gat_bf/sd = x@W1 ; z1: big1 = x@Wm1+bm1 ; agg -> big1, h_bf
    k_gemm2<<<gg2, 512, 0, stream>>>(x_bf, Wt1, gat_bf, as_[0], ad_[0], sdbuf,
                                     Wtm1, bm1, big1, N_NODES, F_IN);
    k_agg<<<agg_grid, 256, 0, stream>>>(gat_bf, sdbuf, off, srcl, bb[0], big1, big1, h_bf);

    // Layer 2
    k_gemm2<<<gg2, 512, 0, stream>>>(h_bf, Wt2, gat_bf, as_[1], ad_[1], sdbuf,
                                     Wtm2, bm2, big2, N_NODES, HID);
    k_agg<<<agg_grid, 256, 0, stream>>>(gat_bf, sdbuf, off, srcl, bb[1], big2, big2, h_bf);

    // Layers 3-5: h = h + relu(gat(h)) in place on big2
    const unsigned short* Wtl[3] = {Wt3, Wt4, Wt5};
    for (int l = 2; l < 5; ++l) {
        k_gemm2<<<gg1, 512, 0, stream>>>(h_bf, Wtl[l - 2], gat_bf, as_[l], ad_[l], sdbuf,
                                         nullptr, nullptr, nullptr, N_NODES, HID);
        k_agg<<<agg_grid, 256, 0, stream>>>(gat_bf, sdbuf, off, srcl, bb[l], big2, big2, h_bf);
    }

    // pool + head
    k_pool<<<G_GRAPHS, HID, 0, stream>>>(big2, batch, pooled);
    k_mlp1<<<dim3(G_GRAPHS, NHID / 64), 64, 0, stream>>>(pooled, Wh1, bh1, z1);
    k_mlp2_ln<<<G_GRAPHS, NOUT, 0, stream>>>(z1, Wh2, bh2, lng, lnb, out);
}